// Round 7
// baseline (156.778 us; speedup 1.0000x reference)
//
#include <hip/hip_runtime.h>
#include <math.h>

#define NB 4      // batch
#define LQ 128
#define LK 512
#define ET 128    // EMBED_TIME
#define NH 8
#define EKD 16    // EK = ET/NH
#define DD 64     // INPUT_DIM
#define HD 256    // HIDDEN_DIM

// workspace layout (floats)
#define QP_OFF 0                         // [NB*LQ][ET]   = 512*128
#define KP_OFF (NB*LQ*ET)                // [NB*LK][ET]   = 2048*128
#define CTX_OFF (KP_OFF + NB*LK*ET)      // [NB*LQ][NH*DD] = 512*512

// ---------------------------------------------------------------------------
// K1: Q = query@Wq + bq ; K = key@Wk + bk
// grid 160 blocks x 256 thr. blocks 0..31 -> Q rows (512), 32..159 -> K rows (2048)
// each block: 16 rows x 128 cols, reduction over 128
// ---------------------------------------------------------------------------
__global__ __launch_bounds__(256) void proj_kernel(
    const float* __restrict__ query, const float* __restrict__ key,
    const float* __restrict__ Wq, const float* __restrict__ bq,
    const float* __restrict__ Wk, const float* __restrict__ bk,
    float* __restrict__ ws)
{
  __shared__ float Xs[16][128];
  const int blk = blockIdx.x;
  const int tid = threadIdx.x;
  const float* X; const float* W; const float* bias; float* outp; int rowbase;
  if (blk < 32) { X = query; W = Wq; bias = bq; outp = ws + QP_OFF; rowbase = blk * 16; }
  else          { X = key;   W = Wk; bias = bk; outp = ws + KP_OFF; rowbase = (blk - 32) * 16; }

  for (int idx = tid; idx < 16 * 32; idx += 256) {
    int r = idx >> 5, c4 = idx & 31;
    ((float4*)(&Xs[r][0]))[c4] = ((const float4*)(X + (size_t)(rowbase + r) * ET))[c4];
  }
  __syncthreads();

  const int r  = tid >> 4;
  const int c0 = (tid & 15) * 8;
  float acc[8] = {0.f,0.f,0.f,0.f,0.f,0.f,0.f,0.f};
  #pragma unroll 4
  for (int kk = 0; kk < ET; ++kk) {
    float x = Xs[r][kk];
    const float* wrow = W + (size_t)kk * ET + c0;
    float4 w0 = *(const float4*)(wrow);
    float4 w1 = *(const float4*)(wrow + 4);
    acc[0] = fmaf(x, w0.x, acc[0]);
    acc[1] = fmaf(x, w0.y, acc[1]);
    acc[2] = fmaf(x, w0.z, acc[2]);
    acc[3] = fmaf(x, w0.w, acc[3]);
    acc[4] = fmaf(x, w1.x, acc[4]);
    acc[5] = fmaf(x, w1.y, acc[5]);
    acc[6] = fmaf(x, w1.z, acc[6]);
    acc[7] = fmaf(x, w1.w, acc[7]);
  }
  float4 bb0 = *(const float4*)(bias + c0);
  float4 bb1 = *(const float4*)(bias + c0 + 4);
  float* orow = outp + (size_t)(rowbase + r) * ET + c0;
  float4 o0 = make_float4(acc[0]+bb0.x, acc[1]+bb0.y, acc[2]+bb0.z, acc[3]+bb0.w);
  float4 o1 = make_float4(acc[4]+bb1.x, acc[5]+bb1.y, acc[6]+bb1.z, acc[7]+bb1.w);
  *(float4*)(orow)     = o0;
  *(float4*)(orow + 4) = o1;
}

// ---------------------------------------------------------------------------
// K2: per (b,h,qtile of 16): scores -> rowmax -> exp -> E@[mask*value, mask]
// grid 256 blocks x 256 thr
// ---------------------------------------------------------------------------
__global__ __launch_bounds__(256) void attn_kernel(
    const float* __restrict__ value, const int* __restrict__ mask,
    float* __restrict__ ws)
{
  __shared__ float Ks[LK][20];     // 16 cols + pad 4 (float4-aligned, 2-way max)
  __shared__ float Qs[16][16];
  __shared__ float Es[16][520];    // 512 + pad 8 (conflict-free stores)

  const float* Qp = ws + QP_OFF;
  const float* Kp = ws + KP_OFF;
  float* ctx = ws + CTX_OFF;

  const int bx = blockIdx.x;
  const int b  = bx >> 6;
  const int h  = (bx >> 3) & 7;
  const int qt = bx & 7;
  const int tid = threadIdx.x;

  // stage K_h: [512][16]
  for (int idx = tid; idx < LK * 4; idx += 256) {
    int k = idx >> 2, j4 = idx & 3;
    float4 v4 = *(const float4*)(Kp + (size_t)(b * LK + k) * ET + h * EKD + j4 * 4);
    *(float4*)(&Ks[k][j4 * 4]) = v4;
  }
  // stage Q tile: [16][16]
  if (tid < 64) {
    int r = tid >> 2, j4 = tid & 3;
    *(float4*)(&Qs[r][j4 * 4]) =
        *(const float4*)(Qp + (size_t)(b * LQ + qt * 16 + r) * ET + h * EKD + j4 * 4);
  }
  __syncthreads();

  // ---- scores + rowmax + exp ----
  {
    const int r = tid >> 4;   // q row 0..15
    const int i = tid & 15;   // k sub-lane
    float qreg[16];
    #pragma unroll
    for (int j = 0; j < 16; ++j) qreg[j] = Qs[r][j];

    float sv[32];
    float smax = -1e30f;
    #pragma unroll 4
    for (int kk = 0; kk < 32; ++kk) {
      int k = kk * 16 + i;
      float4 k0 = *(const float4*)(&Ks[k][0]);
      float4 k1 = *(const float4*)(&Ks[k][4]);
      float4 k2 = *(const float4*)(&Ks[k][8]);
      float4 k3 = *(const float4*)(&Ks[k][12]);
      float dot = qreg[0] * k0.x;
      dot = fmaf(qreg[1],  k0.y, dot);
      dot = fmaf(qreg[2],  k0.z, dot);
      dot = fmaf(qreg[3],  k0.w, dot);
      dot = fmaf(qreg[4],  k1.x, dot);
      dot = fmaf(qreg[5],  k1.y, dot);
      dot = fmaf(qreg[6],  k1.z, dot);
      dot = fmaf(qreg[7],  k1.w, dot);
      dot = fmaf(qreg[8],  k2.x, dot);
      dot = fmaf(qreg[9],  k2.y, dot);
      dot = fmaf(qreg[10], k2.z, dot);
      dot = fmaf(qreg[11], k2.w, dot);
      dot = fmaf(qreg[12], k3.x, dot);
      dot = fmaf(qreg[13], k3.y, dot);
      dot = fmaf(qreg[14], k3.z, dot);
      dot = fmaf(qreg[15], k3.w, dot);
      float s = dot * 0.25f;   // 1/sqrt(EK)
      sv[kk] = s;
      smax = fmaxf(smax, s);
    }
    // reduce max across the 16 lanes covering this row
    #pragma unroll
    for (int off = 1; off < 16; off <<= 1)
      smax = fmaxf(smax, __shfl_xor(smax, off));
    #pragma unroll
    for (int kk = 0; kk < 32; ++kk)
      Es[r][kk * 16 + i] = __expf(sv[kk] - smax);
  }
  __syncthreads();

  // ---- Num/Den contraction over k ----
  {
    const int d  = tid & 63;
    const int qg = tid >> 6;  // 0..3, rows qg*4..qg*4+3
    float num[4] = {0.f,0.f,0.f,0.f};
    float den[4] = {0.f,0.f,0.f,0.f};
    const int*   mrow = mask  + (size_t)(b * LK) * DD + d;
    const float* vrow = value + (size_t)(b * LK) * DD + d;
    #pragma unroll 4
    for (int k = 0; k < LK; ++k) {
      float mf = (float)mrow[(size_t)k * DD];
      float v  = vrow[(size_t)k * DD];
      float mv = mf * v;
      #pragma unroll
      for (int qi = 0; qi < 4; ++qi) {
        float e = Es[qg * 4 + qi][k];
        num[qi] = fmaf(e, mv, num[qi]);
        den[qi] = fmaf(e, mf, den[qi]);
      }
    }
    #pragma unroll
    for (int qi = 0; qi < 4; ++qi) {
      int row = b * LQ + qt * 16 + qg * 4 + qi;
      ctx[(size_t)row * (NH * DD) + h * DD + d] = num[qi] / den[qi];
    }
  }
}

// ---------------------------------------------------------------------------
// K3: out = ctx @ Wo + bo   (512x512)@(512x256)
// grid 128 blocks x 256 thr; block = 16 rows x 64 cols
// ---------------------------------------------------------------------------
__global__ __launch_bounds__(256) void outproj_kernel(
    const float* __restrict__ Wo, const float* __restrict__ bo,
    const float* __restrict__ ws, float* __restrict__ out)
{
  __shared__ float Cs[16][512];
  const float* ctx = ws + CTX_OFF;
  const int bx = blockIdx.x;
  const int rt = bx >> 2;          // 0..31
  const int ct = bx & 3;           // 0..3
  const int r0 = rt * 16, c0 = ct * 64;
  const int tid = threadIdx.x;

  for (int idx = tid; idx < 16 * 128; idx += 256) {
    int r = idx >> 7, c4 = idx & 127;
    *(float4*)(&Cs[r][c4 * 4]) = *(const float4*)(ctx + (size_t)(r0 + r) * 512 + c4 * 4);
  }
  __syncthreads();

  const int c  = c0 + (tid & 63);
  const int rg = tid >> 6;
  float acc[4] = {0.f,0.f,0.f,0.f};
  #pragma unroll 8
  for (int kk = 0; kk < 512; ++kk) {
    float w = Wo[(size_t)kk * HD + c];
    #pragma unroll
    for (int ri = 0; ri < 4; ++ri)
      acc[ri] = fmaf(Cs[rg * 4 + ri][kk], w, acc[ri]);
  }
  const float bb = bo[c];
  #pragma unroll
  for (int ri = 0; ri < 4; ++ri)
    out[(size_t)(r0 + rg * 4 + ri) * HD + c] = acc[ri] + bb;
}

// ---------------------------------------------------------------------------
extern "C" void kernel_launch(void* const* d_in, const int* in_sizes, int n_in,
                              void* d_out, int out_size, void* d_ws, size_t ws_size,
                              hipStream_t stream) {
  const float* query = (const float*)d_in[0];
  const float* key   = (const float*)d_in[1];
  const float* value = (const float*)d_in[2];
  const int*   mask  = (const int*)d_in[3];
  const float* Wq    = (const float*)d_in[4];
  const float* bq    = (const float*)d_in[5];
  const float* Wk    = (const float*)d_in[6];
  const float* bk    = (const float*)d_in[7];
  const float* Wo    = (const float*)d_in[8];
  const float* bo    = (const float*)d_in[9];
  float* out = (float*)d_out;
  float* ws  = (float*)d_ws;

  proj_kernel<<<160, 256, 0, stream>>>(query, key, Wq, bq, Wk, bk, ws);
  attn_kernel<<<256, 256, 0, stream>>>(value, mask, ws);
  outproj_kernel<<<128, 256, 0, stream>>>(Wo, bo, ws, out);
}

// Round 9
// 124.989 us; speedup vs baseline: 1.2543x; 1.2543x over previous
//
#include <hip/hip_runtime.h>
#include <math.h>

#define NB 4      // batch
#define LQ 128
#define LK 512
#define ET 128    // EMBED_TIME
#define NH 8
#define EKD 16    // EK = ET/NH
#define DD 64     // INPUT_DIM
#define HD 256    // HIDDEN_DIM

// workspace layout (floats)
#define QP_OFF 0                         // [NB*LQ][ET]   = 512*128
#define KP_OFF (NB*LQ*ET)                // [NB*LK][ET]   = 2048*128
#define CTX_OFF (KP_OFF + NB*LK*ET)      // [NB*LQ][NH*DD] = 512*512

// ---------------------------------------------------------------------------
// K1: Q = query@Wq + bq ; K = key@Wk + bk   (unchanged from baseline)
// ---------------------------------------------------------------------------
__global__ __launch_bounds__(256) void proj_kernel(
    const float* __restrict__ query, const float* __restrict__ key,
    const float* __restrict__ Wq, const float* __restrict__ bq,
    const float* __restrict__ Wk, const float* __restrict__ bk,
    float* __restrict__ ws)
{
  __shared__ float Xs[16][128];
  const int blk = blockIdx.x;
  const int tid = threadIdx.x;
  const float* X; const float* W; const float* bias; float* outp; int rowbase;
  if (blk < 32) { X = query; W = Wq; bias = bq; outp = ws + QP_OFF; rowbase = blk * 16; }
  else          { X = key;   W = Wk; bias = bk; outp = ws + KP_OFF; rowbase = (blk - 32) * 16; }

  for (int idx = tid; idx < 16 * 32; idx += 256) {
    int r = idx >> 5, c4 = idx & 31;
    ((float4*)(&Xs[r][0]))[c4] = ((const float4*)(X + (size_t)(rowbase + r) * ET))[c4];
  }
  __syncthreads();

  const int r  = tid >> 4;
  const int c0 = (tid & 15) * 8;
  float acc[8] = {0.f,0.f,0.f,0.f,0.f,0.f,0.f,0.f};
  #pragma unroll 4
  for (int kk = 0; kk < ET; ++kk) {
    float x = Xs[r][kk];
    const float* wrow = W + (size_t)kk * ET + c0;
    float4 w0 = *(const float4*)(wrow);
    float4 w1 = *(const float4*)(wrow + 4);
    acc[0] = fmaf(x, w0.x, acc[0]);
    acc[1] = fmaf(x, w0.y, acc[1]);
    acc[2] = fmaf(x, w0.z, acc[2]);
    acc[3] = fmaf(x, w0.w, acc[3]);
    acc[4] = fmaf(x, w1.x, acc[4]);
    acc[5] = fmaf(x, w1.y, acc[5]);
    acc[6] = fmaf(x, w1.z, acc[6]);
    acc[7] = fmaf(x, w1.w, acc[7]);
  }
  float4 bb0 = *(const float4*)(bias + c0);
  float4 bb1 = *(const float4*)(bias + c0 + 4);
  float* orow = outp + (size_t)(rowbase + r) * ET + c0;
  float4 o0 = make_float4(acc[0]+bb0.x, acc[1]+bb0.y, acc[2]+bb0.z, acc[3]+bb0.w);
  float4 o1 = make_float4(acc[4]+bb1.x, acc[5]+bb1.y, acc[6]+bb1.z, acc[7]+bb1.w);
  *(float4*)(orow)     = o0;
  *(float4*)(orow + 4) = o1;
}

// ---------------------------------------------------------------------------
// K2: per (b,h,qtile of 16): scores -> rowmax -> exp -> E@[mask*value, mask]
// grid 256 blocks x 256 thr.  Num/Den phase is wave-split over k:
// wave w handles k in [w*128, w*128+128), each thread keeps 16 rows of
// (num,den) in registers; cross-wave reduction via LDS partials aliased
// over the dead K-tile buffer.
// ---------------------------------------------------------------------------
__global__ __launch_bounds__(256) void attn_kernel(
    const float* __restrict__ value, const int* __restrict__ mask,
    float* __restrict__ ws)
{
  // Buf: phases A/B = Ks[512][20] (40 KB). phase C = partials:
  //   num at [0 .. 4095]  = [w][r][d] = ((w*16+r)*64+d)
  //   den at [4096..8191]
  __shared__ float Buf[10240];
  __shared__ float Qs[16][16];
  __shared__ float Es[16][520];    // 512 + pad 8; rows 16B-aligned (2080 B)

  const float* Qp = ws + QP_OFF;
  const float* Kp = ws + KP_OFF;
  float* ctx = ws + CTX_OFF;

  const int bx = blockIdx.x;
  const int b  = bx >> 6;
  const int h  = (bx >> 3) & 7;
  const int qt = bx & 7;
  const int tid = threadIdx.x;

  // ---- stage K_h: [512][16] into Buf (stride 20) ----
  for (int idx = tid; idx < LK * 4; idx += 256) {
    int k = idx >> 2, j4 = idx & 3;
    float4 v4 = *(const float4*)(Kp + (size_t)(b * LK + k) * ET + h * EKD + j4 * 4);
    *(float4*)(&Buf[k * 20 + j4 * 4]) = v4;
  }
  if (tid < 64) {
    int r = tid >> 2, j4 = tid & 3;
    *(float4*)(&Qs[r][j4 * 4]) =
        *(const float4*)(Qp + (size_t)(b * LQ + qt * 16 + r) * ET + h * EKD + j4 * 4);
  }
  __syncthreads();

  // ---- scores + rowmax + exp ----
  {
    const int r = tid >> 4;   // q row 0..15
    const int i = tid & 15;   // k sub-lane
    float qreg[16];
    #pragma unroll
    for (int j = 0; j < 16; ++j) qreg[j] = Qs[r][j];

    float sv[32];
    float smax = -1e30f;
    #pragma unroll 4
    for (int kk = 0; kk < 32; ++kk) {
      int k = kk * 16 + i;
      const float* kp = &Buf[k * 20];
      float4 k0 = *(const float4*)(kp);
      float4 k1 = *(const float4*)(kp + 4);
      float4 k2 = *(const float4*)(kp + 8);
      float4 k3 = *(const float4*)(kp + 12);
      float dot = qreg[0] * k0.x;
      dot = fmaf(qreg[1],  k0.y, dot);
      dot = fmaf(qreg[2],  k0.z, dot);
      dot = fmaf(qreg[3],  k0.w, dot);
      dot = fmaf(qreg[4],  k1.x, dot);
      dot = fmaf(qreg[5],  k1.y, dot);
      dot = fmaf(qreg[6],  k1.z, dot);
      dot = fmaf(qreg[7],  k1.w, dot);
      dot = fmaf(qreg[8],  k2.x, dot);
      dot = fmaf(qreg[9],  k2.y, dot);
      dot = fmaf(qreg[10], k2.z, dot);
      dot = fmaf(qreg[11], k2.w, dot);
      dot = fmaf(qreg[12], k3.x, dot);
      dot = fmaf(qreg[13], k3.y, dot);
      dot = fmaf(qreg[14], k3.z, dot);
      dot = fmaf(qreg[15], k3.w, dot);
      float s = dot * 0.25f;   // 1/sqrt(EK)
      sv[kk] = s;
      smax = fmaxf(smax, s);
    }
    #pragma unroll
    for (int off = 1; off < 16; off <<= 1)
      smax = fmaxf(smax, __shfl_xor(smax, off));
    #pragma unroll
    for (int kk = 0; kk < 32; ++kk)
      Es[r][kk * 16 + i] = __expf(sv[kk] - smax);
  }
  __syncthreads();   // Es ready; all Ks reads done -> Buf reusable

  // ---- Num/Den, wave-split over k ----
  {
    const int w = tid >> 6;   // wave 0..3 -> k slice
    const int d = tid & 63;
    float num[16], den[16];
    #pragma unroll
    for (int r = 0; r < 16; ++r) { num[r] = 0.f; den[r] = 0.f; }

    const int*   mcol = mask  + (size_t)b * LK * DD + d;
    const float* vcol = value + (size_t)b * LK * DD + d;
    const int kbase = w * 128;

    #pragma unroll 2
    for (int kb = 0; kb < 32; ++kb) {
      const int k = kbase + kb * 4;
      float m0 = (float)mcol[(size_t)(k + 0) * DD];
      float m1 = (float)mcol[(size_t)(k + 1) * DD];
      float m2 = (float)mcol[(size_t)(k + 2) * DD];
      float m3 = (float)mcol[(size_t)(k + 3) * DD];
      float v0 = vcol[(size_t)(k + 0) * DD];
      float v1 = vcol[(size_t)(k + 1) * DD];
      float v2 = vcol[(size_t)(k + 2) * DD];
      float v3 = vcol[(size_t)(k + 3) * DD];
      float mv0 = m0 * v0, mv1 = m1 * v1, mv2 = m2 * v2, mv3 = m3 * v3;
      #pragma unroll
      for (int r = 0; r < 16; ++r) {
        float4 e = *(const float4*)(&Es[r][k]);   // broadcast b128, conflict-free
        num[r] = fmaf(e.x, mv0, num[r]);
        num[r] = fmaf(e.y, mv1, num[r]);
        num[r] = fmaf(e.z, mv2, num[r]);
        num[r] = fmaf(e.w, mv3, num[r]);
        den[r] = fmaf(e.x, m0, den[r]);
        den[r] = fmaf(e.y, m1, den[r]);
        den[r] = fmaf(e.z, m2, den[r]);
        den[r] = fmaf(e.w, m3, den[r]);
      }
    }
    // write partials (banks: d%32 -> 2-way, free)
    #pragma unroll
    for (int r = 0; r < 16; ++r) {
      Buf[(w * 16 + r) * 64 + d]        = num[r];
      Buf[4096 + (w * 16 + r) * 64 + d] = den[r];
    }
  }
  __syncthreads();

  // ---- cross-wave reduce + ctx write ----
  {
    const int d  = tid & 63;
    const int rg = tid >> 6;
    #pragma unroll
    for (int j = 0; j < 4; ++j) {
      const int r = rg * 4 + j;
      float n = Buf[(r)      * 64 + d] + Buf[(16 + r) * 64 + d]
              + Buf[(32 + r) * 64 + d] + Buf[(48 + r) * 64 + d];
      float dn = Buf[4096 + (r)      * 64 + d] + Buf[4096 + (16 + r) * 64 + d]
               + Buf[4096 + (32 + r) * 64 + d] + Buf[4096 + (48 + r) * 64 + d];
      const int row = b * LQ + qt * 16 + r;
      ctx[(size_t)row * (NH * DD) + h * DD + d] = n / dn;
    }
  }
}

// ---------------------------------------------------------------------------
// K3: out = ctx @ Wo + bo   (512x512)@(512x256)
// grid 128 blocks x 256 thr; block = 16 rows x 64 cols, wave-split over k
// ---------------------------------------------------------------------------
__global__ __launch_bounds__(256) void outproj_kernel(
    const float* __restrict__ Wo, const float* __restrict__ bo,
    const float* __restrict__ ws, float* __restrict__ out)
{
  __shared__ float Cs[16][512];     // 32 KB; rows 2048 B -> float4-aligned
  __shared__ float Pn[4][16][64];   // 16 KB partials
  const float* ctx = ws + CTX_OFF;
  const int bx = blockIdx.x;
  const int rt = bx >> 2;          // 0..31
  const int ct = bx & 3;           // 0..3
  const int r0 = rt * 16, c0 = ct * 64;
  const int tid = threadIdx.x;

  for (int idx = tid; idx < 16 * 128; idx += 256) {
    int r = idx >> 7, c4 = idx & 127;
    *(float4*)(&Cs[r][c4 * 4]) = *(const float4*)(ctx + (size_t)(r0 + r) * 512 + c4 * 4);
  }
  __syncthreads();

  const int w    = tid >> 6;        // wave 0..3 -> k slice
  const int lane = tid & 63;
  const int c    = c0 + lane;
  float acc[16];
  #pragma unroll
  for (int r = 0; r < 16; ++r) acc[r] = 0.f;

  const int kbase = w * 128;
  #pragma unroll 2
  for (int kb = 0; kb < 32; ++kb) {
    const int k = kbase + kb * 4;
    float w0 = Wo[(size_t)(k + 0) * HD + c];
    float w1 = Wo[(size_t)(k + 1) * HD + c];
    float w2 = Wo[(size_t)(k + 2) * HD + c];
    float w3 = Wo[(size_t)(k + 3) * HD + c];
    #pragma unroll
    for (int r = 0; r < 16; ++r) {
      float4 cs = *(const float4*)(&Cs[r][k]);   // broadcast b128
      acc[r] = fmaf(cs.x, w0, acc[r]);
      acc[r] = fmaf(cs.y, w1, acc[r]);
      acc[r] = fmaf(cs.z, w2, acc[r]);
      acc[r] = fmaf(cs.w, w3, acc[r]);
    }
  }
  #pragma unroll
  for (int r = 0; r < 16; ++r) Pn[w][r][lane] = acc[r];
  __syncthreads();

  {
    const int rg = tid >> 6;
    const float bb = bo[c0 + (tid & 63)];
    #pragma unroll
    for (int j = 0; j < 4; ++j) {
      const int r = rg * 4 + j;
      float s = Pn[0][r][tid & 63] + Pn[1][r][tid & 63]
              + Pn[2][r][tid & 63] + Pn[3][r][tid & 63];
      out[(size_t)(r0 + r) * HD + c0 + (tid & 63)] = s + bb;
    }
  }
}

// ---------------------------------------------------------------------------
extern "C" void kernel_launch(void* const* d_in, const int* in_sizes, int n_in,
                              void* d_out, int out_size, void* d_ws, size_t ws_size,
                              hipStream_t stream) {
  const float* query = (const float*)d_in[0];
  const float* key   = (const float*)d_in[1];
  const float* value = (const float*)d_in[2];
  const int*   mask  = (const int*)d_in[3];
  const float* Wq    = (const float*)d_in[4];
  const float* bq    = (const float*)d_in[5];
  const float* Wk    = (const float*)d_in[6];
  const float* bk    = (const float*)d_in[7];
  const float* Wo    = (const float*)d_in[8];
  const float* bo    = (const float*)d_in[9];
  float* out = (float*)d_out;
  float* ws  = (float*)d_ws;

  proj_kernel<<<160, 256, 0, stream>>>(query, key, Wq, bq, Wk, bk, ws);
  attn_kernel<<<256, 256, 0, stream>>>(value, mask, ws);
  outproj_kernel<<<128, 256, 0, stream>>>(Wo, bo, ws, out);
}